// Round 10
// baseline (540.181 us; speedup 1.0000x reference)
//
#include <hip/hip_runtime.h>
#include <hip/hip_bf16.h>
#include <math.h>

#define NN   10000
#define EE   160000
#define CC   128
#define RBFD 20
#define HIDD 32
#define WND  384
#define MROW 1152   // 9*128 accumulator row
#define RS   384    // sorted u-row stride (floats) = 1536 B, line-aligned

// Static device buffers (fully rewritten each call).
__device__ __align__(16) float g_row[(size_t)EE * RS];    // 245.8 MB: sorted u=[u0|u1|u2]
__device__ __align__(16) float g_proj[(size_t)NN * 64];   // 2.6 MB: per-node Pi(32,+bs1)|Pj(32)
__device__ __align__(16) float g_accu[(size_t)NN * MROW]; // 46 MB
__device__ int g_deg[NN];
__device__ int g_offs[NN + 1];
__device__ int g_rel[EE];
__device__ int g_ord[EE];   // sorted row -> original edge

__device__ __forceinline__ float silu_f(float x) { return x / (1.f + __expf(-x)); }

__global__ __launch_bounds__(256) void zero_deg_kernel()
{
    int i = blockIdx.x * 256 + threadIdx.x;
    if (i < NN) g_deg[i] = 0;
}

__global__ __launch_bounds__(256) void hist_kernel(const int* __restrict__ edge_index)
{
    int e = blockIdx.x * 256 + threadIdx.x;
    if (e < EE) g_rel[e] = atomicAdd(&g_deg[edge_index[e]], 1);
}

// Blocked scan: 256 threads x 40 items, one block.
__global__ __launch_bounds__(256) void scan_kernel()
{
    __shared__ int sP[256];
    int t = threadIdx.x;
    int lo = t * 40, hi = min(lo + 40, NN);
    int sum = 0;
    for (int i = lo; i < hi; ++i) sum += g_deg[i];
    sP[t] = sum;
    __syncthreads();
    for (int off = 1; off < 256; off <<= 1) {
        int v = (t >= off) ? sP[t - off] : 0;
        __syncthreads();
        sP[t] += v;
        __syncthreads();
    }
    int run = sP[t] - sum;   // exclusive prefix
    if (t == 0) g_offs[0] = 0;
    for (int i = lo; i < hi; ++i) { run += g_deg[i]; g_offs[i + 1] = run; }
}

__global__ __launch_bounds__(256) void perm_kernel(const int* __restrict__ edge_index)
{
    int e = blockIdx.x * 256 + threadIdx.x;
    if (e < EE) g_ord[g_offs[edge_index[e]] + g_rel[e]] = e;
}

// Per-node halves of MLP1: Pi = nf@Ws1[0:128]+bs1, Pj = nf@Ws1[128:256].
__global__ __launch_bounds__(64) void proj_kernel(
    const float* __restrict__ nf,
    const float* __restrict__ Ws1, const float* __restrict__ bs1)
{
    int n = blockIdx.x * 64 + threadIdx.x;
    if (n >= NN) return;
    float Pi[HIDD], Pj[HIDD];
    #pragma unroll
    for (int j = 0; j < HIDD; ++j) { Pi[j] = bs1[j]; Pj[j] = 0.f; }
    const float4* x4 = reinterpret_cast<const float4*>(nf + (size_t)n * CC);
    #pragma unroll 1
    for (int k4 = 0; k4 < CC / 4; ++k4) {
        float4 a = x4[k4];
        const float* wi = Ws1 + (4 * k4) * HIDD;
        const float* wj = Ws1 + (CC + 4 * k4) * HIDD;
        #pragma unroll
        for (int j = 0; j < HIDD; ++j) {
            Pi[j] = fmaf(a.x, wi[j], Pi[j]);
            Pi[j] = fmaf(a.y, wi[HIDD + j], Pi[j]);
            Pi[j] = fmaf(a.z, wi[2 * HIDD + j], Pi[j]);
            Pi[j] = fmaf(a.w, wi[3 * HIDD + j], Pi[j]);
            Pj[j] = fmaf(a.x, wj[j], Pj[j]);
            Pj[j] = fmaf(a.y, wj[HIDD + j], Pj[j]);
            Pj[j] = fmaf(a.z, wj[2 * HIDD + j], Pj[j]);
            Pj[j] = fmaf(a.w, wj[3 * HIDD + j], Pj[j]);
        }
    }
    float* o = g_proj + (size_t)n * 64;
    #pragma unroll
    for (int j = 0; j < HIDD; ++j) { o[j] = Pi[j]; o[HIDD + j] = Pj[j]; }
}

// Edge MLP, sorted order, lane=edge, single-wave blocks. Block = (64-edge
// group) x (192-col half). Two-pass LDS weight staging, fully unrolled
// compute, hoisted xj, float4 full-line dump.
__global__ __launch_bounds__(64) void mlp_kernel(
    const float* __restrict__ nf,
    const float* __restrict__ edge_attr,
    const int*   __restrict__ edge_index,
    const float* __restrict__ Ws2, const float* __restrict__ bs2,
    const float* __restrict__ Wr1, const float* __restrict__ br1,
    const float* __restrict__ Wr2, const float* __restrict__ br2)
{
    __shared__ float sW[32][36];   // 4.6 KB: one matrix 32-col chunk
    __shared__ float sT[64][33];   // 8.4 KB: 64-edge x 32-col transpose tile

    int half = blockIdx.x & 1;
    int bg   = blockIdx.x >> 1;
    int l = threadIdx.x;
    int p = bg * 64 + l;
    int e = g_ord[p];
    int s = edge_index[e];
    int t = edge_index[EE + e];

    // ---- hs = silu(Pi[s] + Pj[t])
    float hs[HIDD];
    {
        const float4* pi = reinterpret_cast<const float4*>(g_proj + (size_t)s * 64);
        const float4* pj = reinterpret_cast<const float4*>(g_proj + (size_t)t * 64 + HIDD);
        #pragma unroll
        for (int j4 = 0; j4 < HIDD / 4; ++j4) {
            float4 a = pi[j4], b = pj[j4];
            hs[4 * j4 + 0] = silu_f(a.x + b.x);
            hs[4 * j4 + 1] = silu_f(a.y + b.y);
            hs[4 * j4 + 2] = silu_f(a.z + b.z);
            hs[4 * j4 + 3] = silu_f(a.w + b.w);
        }
    }

    // ---- hr = silu(edge_attr @ Wr1 + br1)
    float hr[HIDD];
    #pragma unroll
    for (int j = 0; j < HIDD; ++j) hr[j] = br1[j];
    #pragma unroll 1
    for (int k4 = 0; k4 < RBFD / 4; ++k4) {
        float4 a = reinterpret_cast<const float4*>(edge_attr + (size_t)e * RBFD)[k4];
        const float* wp = Wr1 + (4 * k4) * HIDD;
        #pragma unroll
        for (int j = 0; j < HIDD; ++j) {
            hr[j] = fmaf(a.x, wp[j], hr[j]);
            hr[j] = fmaf(a.y, wp[HIDD + j], hr[j]);
            hr[j] = fmaf(a.z, wp[2 * HIDD + j], hr[j]);
            hr[j] = fmaf(a.w, wp[3 * HIDD + j], hr[j]);
        }
    }
    #pragma unroll
    for (int j = 0; j < HIDD; ++j) hr[j] = silu_f(hr[j]);

    const float4* nf4 = reinterpret_cast<const float4*>(nf);
    size_t rowbase = (size_t)bg * 64 * RS;
    int jj = l >> 1, qq = l & 1;   // staging decomposition

    #pragma unroll 1
    for (int chh = 0; chh < 6; ++chh) {
        int ch = half * 6 + chh;
        int c0 = ch * 32;                       // global col base
        int xb = (c0 & (CC - 1)) >> 2;          // xj float4 base

        // hoist xj for this chunk (8 independent loads, one wait)
        float4 xjv[8];
        #pragma unroll
        for (int k = 0; k < 8; ++k)
            xjv[k] = nf4[(size_t)t * (CC / 4) + xb + k];

        // ---- pass A: stage Ws2 chunk, compute as[32]
        {
            const float4* src = reinterpret_cast<const float4*>(
                Ws2 + (size_t)jj * WND + c0 + qq * 16);
            float4* dst = reinterpret_cast<float4*>(&sW[jj][qq * 16]);
            dst[0] = src[0]; dst[1] = src[1]; dst[2] = src[2]; dst[3] = src[3];
        }
        __syncthreads();

        float as[32];
        #pragma unroll
        for (int c4 = 0; c4 < 8; ++c4) {
            float a0 = bs2[c0 + c4 * 4 + 0], a1 = bs2[c0 + c4 * 4 + 1];
            float a2 = bs2[c0 + c4 * 4 + 2], a3 = bs2[c0 + c4 * 4 + 3];
            #pragma unroll
            for (int jg = 0; jg < 8; ++jg) {
                float4 wv[4];
                #pragma unroll
                for (int k = 0; k < 4; ++k)
                    wv[k] = *reinterpret_cast<const float4*>(&sW[jg * 4 + k][c4 * 4]);
                #pragma unroll
                for (int k = 0; k < 4; ++k) {
                    float h = hs[jg * 4 + k];
                    a0 = fmaf(h, wv[k].x, a0); a1 = fmaf(h, wv[k].y, a1);
                    a2 = fmaf(h, wv[k].z, a2); a3 = fmaf(h, wv[k].w, a3);
                }
            }
            as[c4 * 4 + 0] = a0; as[c4 * 4 + 1] = a1;
            as[c4 * 4 + 2] = a2; as[c4 * 4 + 3] = a3;
        }
        __syncthreads();

        // ---- pass B: stage Wr2 chunk, compute ar, u -> sT
        {
            const float4* src = reinterpret_cast<const float4*>(
                Wr2 + (size_t)jj * WND + c0 + qq * 16);
            float4* dst = reinterpret_cast<float4*>(&sW[jj][qq * 16]);
            dst[0] = src[0]; dst[1] = src[1]; dst[2] = src[2]; dst[3] = src[3];
        }
        __syncthreads();

        #pragma unroll
        for (int c4 = 0; c4 < 8; ++c4) {
            float r0 = br2[c0 + c4 * 4 + 0], r1 = br2[c0 + c4 * 4 + 1];
            float r2 = br2[c0 + c4 * 4 + 2], r3 = br2[c0 + c4 * 4 + 3];
            #pragma unroll
            for (int jg = 0; jg < 8; ++jg) {
                float4 rv[4];
                #pragma unroll
                for (int k = 0; k < 4; ++k)
                    rv[k] = *reinterpret_cast<const float4*>(&sW[jg * 4 + k][c4 * 4]);
                #pragma unroll
                for (int k = 0; k < 4; ++k) {
                    float h = hr[jg * 4 + k];
                    r0 = fmaf(h, rv[k].x, r0); r1 = fmaf(h, rv[k].y, r1);
                    r2 = fmaf(h, rv[k].z, r2); r3 = fmaf(h, rv[k].w, r3);
                }
            }
            sT[l][c4 * 4 + 0] = as[c4 * 4 + 0] * r0 * xjv[c4].x;
            sT[l][c4 * 4 + 1] = as[c4 * 4 + 1] * r1 * xjv[c4].y;
            sT[l][c4 * 4 + 2] = as[c4 * 4 + 2] * r2 * xjv[c4].z;
            sT[l][c4 * 4 + 3] = as[c4 * 4 + 3] * r3 * xjv[c4].w;
        }
        __syncthreads();

        // ---- dump: float4-assembled, 8 full 128B lines per iteration
        int rr = l >> 3, kk = l & 7;
        #pragma unroll
        for (int it = 0; it < 8; ++it) {
            int r = it * 8 + rr;
            float4 v = make_float4(sT[r][kk * 4 + 0], sT[r][kk * 4 + 1],
                                   sT[r][kk * 4 + 2], sT[r][kk * 4 + 3]);
            *reinterpret_cast<float4*>(&g_row[rowbase + (size_t)r * RS + c0 + kk * 4]) = v;
        }
        __syncthreads();
    }
}

// Streaming segmented sum: wave per node, lane = 2 channels.
__global__ __launch_bounds__(512) void gather_kernel(const float* __restrict__ edge_rsh)
{
    int wv = threadIdx.x >> 6, l = threadIdx.x & 63;
    int n = blockIdx.x * 8 + wv;                 // grid exact: NN/8
    int beg = g_offs[n], end = g_offs[n + 1];

    float acc[9][2] = {};
    int r = beg;
    for (; r + 1 < end; r += 2) {
        const float* R0 = g_row + (size_t)r * RS;
        const float* R1 = R0 + RS;
        int e0 = g_ord[r], e1 = g_ord[r + 1];
        const float* Y0 = edge_rsh + (size_t)e0 * 9;
        const float* Y1 = edge_rsh + (size_t)e1 * 9;
        float a0 = R0[l], a1 = R0[64 + l], a2 = R0[128 + l];
        float a3 = R0[192 + l], a4 = R0[256 + l], a5 = R0[320 + l];
        float b0 = R1[l], b1 = R1[64 + l], b2 = R1[128 + l];
        float b3 = R1[192 + l], b4 = R1[256 + l], b5 = R1[320 + l];
        #pragma unroll
        for (int k = 0; k < 9; ++k) {
            float y0 = Y0[k], y1 = Y1[k];
            float ua = (k == 0) ? a0 : (k < 4) ? a2 : a4;
            float ub = (k == 0) ? a1 : (k < 4) ? a3 : a5;
            float va = (k == 0) ? b0 : (k < 4) ? b2 : b4;
            float vb = (k == 0) ? b1 : (k < 4) ? b3 : b5;
            acc[k][0] = fmaf(ua, y0, acc[k][0]);
            acc[k][1] = fmaf(ub, y0, acc[k][1]);
            acc[k][0] = fmaf(va, y1, acc[k][0]);
            acc[k][1] = fmaf(vb, y1, acc[k][1]);
        }
    }
    if (r < end) {
        const float* R0 = g_row + (size_t)r * RS;
        int e0 = g_ord[r];
        const float* Y0 = edge_rsh + (size_t)e0 * 9;
        float a0 = R0[l], a1 = R0[64 + l], a2 = R0[128 + l];
        float a3 = R0[192 + l], a4 = R0[256 + l], a5 = R0[320 + l];
        #pragma unroll
        for (int k = 0; k < 9; ++k) {
            float y0 = Y0[k];
            float ua = (k == 0) ? a0 : (k < 4) ? a2 : a4;
            float ub = (k == 0) ? a1 : (k < 4) ? a3 : a5;
            acc[k][0] = fmaf(ua, y0, acc[k][0]);
            acc[k][1] = fmaf(ub, y0, acc[k][1]);
        }
    }

    float* A = g_accu + (size_t)n * MROW;
    #pragma unroll
    for (int m = 0; m < 9; ++m) {
        A[m * CC + l]      = acc[m][0];
        A[m * CC + 64 + l] = acc[m][1];
    }
}

// Node-wise linear, 2 nodes per block. (unchanged)
__global__ __launch_bounds__(256) void lin2_kernel(
    const float* __restrict__ W0, const float* __restrict__ b0,
    const float* __restrict__ W1, const float* __restrict__ W2,
    float* __restrict__ out)
{
    __shared__ float sA[2 * MROW];
    int n0 = blockIdx.x * 2;
    const float4* g = reinterpret_cast<const float4*>(g_accu + (size_t)n0 * MROW);
    for (int i = threadIdx.x; i < 2 * MROW / 4; i += 256)
        reinterpret_cast<float4*>(sA)[i] = g[i];
    __syncthreads();

    int d  = threadIdx.x & (CC - 1);
    int nl = threadIdx.x >> 7;
    const float* a = sA + nl * MROW;

    float acc[9];
    #pragma unroll
    for (int m = 0; m < 9; ++m) acc[m] = 0.f;

    #pragma unroll 2
    for (int cc = 0; cc < CC; ++cc) {
        float w0 = W0[cc * CC + d];
        float w1 = W1[cc * CC + d];
        float w2 = W2[cc * CC + d];
        acc[0] = fmaf(a[cc],           w0, acc[0]);
        acc[1] = fmaf(a[CC + cc],      w1, acc[1]);
        acc[2] = fmaf(a[2 * CC + cc],  w1, acc[2]);
        acc[3] = fmaf(a[3 * CC + cc],  w1, acc[3]);
        acc[4] = fmaf(a[4 * CC + cc],  w2, acc[4]);
        acc[5] = fmaf(a[5 * CC + cc],  w2, acc[5]);
        acc[6] = fmaf(a[6 * CC + cc],  w2, acc[6]);
        acc[7] = fmaf(a[7 * CC + cc],  w2, acc[7]);
        acc[8] = fmaf(a[8 * CC + cc],  w2, acc[8]);
    }

    const float inv = 0.08838834764831845f;  // 1/sqrt(128)
    size_t ob = (size_t)(n0 + nl) * MROW;
    out[ob + d] = acc[0] * inv + b0[d];
    #pragma unroll
    for (int m = 0; m < 3; ++m) out[ob + CC + d * 3 + m]     = acc[1 + m] * inv;
    #pragma unroll
    for (int m = 0; m < 5; ++m) out[ob + 4 * CC + d * 5 + m] = acc[4 + m] * inv;
}

extern "C" void kernel_launch(void* const* d_in, const int* in_sizes, int n_in,
                              void* d_out, int out_size, void* d_ws, size_t ws_size,
                              hipStream_t stream)
{
    const float* node_feat  = (const float*)d_in[0];
    const float* edge_attr  = (const float*)d_in[1];
    const float* edge_rsh   = (const float*)d_in[2];
    const int*   edge_index = (const int*)  d_in[3];
    const float* Ws1 = (const float*)d_in[4];
    const float* bs1 = (const float*)d_in[5];
    const float* Ws2 = (const float*)d_in[6];
    const float* bs2 = (const float*)d_in[7];
    const float* Wr1 = (const float*)d_in[8];
    const float* br1 = (const float*)d_in[9];
    const float* Wr2 = (const float*)d_in[10];
    const float* br2 = (const float*)d_in[11];
    const float* W0  = (const float*)d_in[12];
    const float* b0  = (const float*)d_in[13];
    const float* W1  = (const float*)d_in[14];
    const float* W2  = (const float*)d_in[15];
    float* out = (float*)d_out;

    zero_deg_kernel<<<(NN + 255) / 256, 256, 0, stream>>>();
    hist_kernel<<<EE / 256, 256, 0, stream>>>(edge_index);
    scan_kernel<<<1, 256, 0, stream>>>();
    perm_kernel<<<EE / 256, 256, 0, stream>>>(edge_index);
    proj_kernel<<<(NN + 63) / 64, 64, 0, stream>>>(node_feat, Ws1, bs1);
    mlp_kernel<<<2 * (EE / 64), 64, 0, stream>>>(
        node_feat, edge_attr, edge_index, Ws2, bs2, Wr1, br1, Wr2, br2);
    gather_kernel<<<NN / 8, 512, 0, stream>>>(edge_rsh);
    lin2_kernel<<<NN / 2, 256, 0, stream>>>(W0, b0, W1, W2, out);
}

// Round 11
// 514.041 us; speedup vs baseline: 1.0509x; 1.0509x over previous
//
#include <hip/hip_runtime.h>
#include <hip/hip_bf16.h>
#include <math.h>

#define NN   10000
#define EE   160000
#define CC   128
#define RBFD 20
#define HIDD 32
#define WND  384
#define MROW 1152   // 9*128 accumulator row: [m=0..8][c=0..127]

// Static device buffers (fully rewritten each call).
__device__ __align__(16) float g_proj[(size_t)NN * 64];   // 2.6 MB: Pi(32,+bs1)|Pj(32)
__device__ __align__(16) float g_accu[(size_t)NN * MROW]; // 46 MB, atomically accumulated
__device__ int g_deg[NN];
__device__ int g_offs[NN + 1];
__device__ int g_rel[EE];
__device__ int g_ord[EE];   // sorted row -> original edge

__device__ __forceinline__ float silu_f(float x) { return x / (1.f + __expf(-x)); }

__global__ __launch_bounds__(256) void zero_deg_kernel()
{
    int i = blockIdx.x * 256 + threadIdx.x;
    if (i < NN) g_deg[i] = 0;
}

__global__ __launch_bounds__(256) void zero_accu_kernel()
{
    float4* p = reinterpret_cast<float4*>(g_accu);
    float4 z = make_float4(0.f, 0.f, 0.f, 0.f);
    int n4 = NN * MROW / 4;
    for (int i = blockIdx.x * 256 + threadIdx.x; i < n4; i += gridDim.x * 256)
        p[i] = z;
}

__global__ __launch_bounds__(256) void hist_kernel(const int* __restrict__ edge_index)
{
    int e = blockIdx.x * 256 + threadIdx.x;
    if (e < EE) g_rel[e] = atomicAdd(&g_deg[edge_index[e]], 1);
}

// Blocked scan: 256 threads x 40 items, one block.
__global__ __launch_bounds__(256) void scan_kernel()
{
    __shared__ int sP[256];
    int t = threadIdx.x;
    int lo = t * 40, hi = min(lo + 40, NN);
    int sum = 0;
    for (int i = lo; i < hi; ++i) sum += g_deg[i];
    sP[t] = sum;
    __syncthreads();
    for (int off = 1; off < 256; off <<= 1) {
        int v = (t >= off) ? sP[t - off] : 0;
        __syncthreads();
        sP[t] += v;
        __syncthreads();
    }
    int run = sP[t] - sum;   // exclusive prefix
    if (t == 0) g_offs[0] = 0;
    for (int i = lo; i < hi; ++i) { run += g_deg[i]; g_offs[i + 1] = run; }
}

__global__ __launch_bounds__(256) void perm_kernel(const int* __restrict__ edge_index)
{
    int e = blockIdx.x * 256 + threadIdx.x;
    if (e < EE) g_ord[g_offs[edge_index[e]] + g_rel[e]] = e;
}

// Per-node halves of MLP1: Pi = nf@Ws1[0:128]+bs1, Pj = nf@Ws1[128:256].
__global__ __launch_bounds__(64) void proj_kernel(
    const float* __restrict__ nf,
    const float* __restrict__ Ws1, const float* __restrict__ bs1)
{
    int n = blockIdx.x * 64 + threadIdx.x;
    if (n >= NN) return;
    float Pi[HIDD], Pj[HIDD];
    #pragma unroll
    for (int j = 0; j < HIDD; ++j) { Pi[j] = bs1[j]; Pj[j] = 0.f; }
    const float4* x4 = reinterpret_cast<const float4*>(nf + (size_t)n * CC);
    #pragma unroll 1
    for (int k4 = 0; k4 < CC / 4; ++k4) {
        float4 a = x4[k4];
        const float* wi = Ws1 + (4 * k4) * HIDD;
        const float* wj = Ws1 + (CC + 4 * k4) * HIDD;
        #pragma unroll
        for (int j = 0; j < HIDD; ++j) {
            Pi[j] = fmaf(a.x, wi[j], Pi[j]);
            Pi[j] = fmaf(a.y, wi[HIDD + j], Pi[j]);
            Pi[j] = fmaf(a.z, wi[2 * HIDD + j], Pi[j]);
            Pi[j] = fmaf(a.w, wi[3 * HIDD + j], Pi[j]);
            Pj[j] = fmaf(a.x, wj[j], Pj[j]);
            Pj[j] = fmaf(a.y, wj[HIDD + j], Pj[j]);
            Pj[j] = fmaf(a.z, wj[2 * HIDD + j], Pj[j]);
            Pj[j] = fmaf(a.w, wj[3 * HIDD + j], Pj[j]);
        }
    }
    float* o = g_proj + (size_t)n * 64;
    #pragma unroll
    for (int j = 0; j < HIDD; ++j) { o[j] = Pi[j]; o[HIDD + j] = Pj[j]; }
}

// Fused edge MLP2 + message + segment-sum. 128-thr blocks (2 waves), lane =
// sorted edge slot. Per 32-col chunk: stage weights in LDS (R9 structure),
// compute u = w_s*w_r*xj into per-wave sT, then in-wave segmented reduction
// over the 64 sorted edges with coalesced atomicAdd flushes into g_accu.
// Section SEC: K y-components, y base YB, accu row offset MOFF.
#define CHUNK_SECTION(SEC, K, YB, MOFF)                                          \
  _Pragma("unroll 1")                                                            \
  for (int chh = 0; chh < 4; ++chh) {                                            \
    const int c0  = SEC * 128 + chh * 32;                                        \
    const int cc0 = chh * 32;                                                    \
    __syncthreads();                                                             \
    {                                                                            \
      const float4* srcW = reinterpret_cast<const float4*>(                      \
          (threadIdx.x >= 64 ? Wr2 : Ws2) + (size_t)jj * WND + c0 + qq * 16);    \
      float4* dstW = reinterpret_cast<float4*>(&sW[threadIdx.x >> 6][jj][qq * 16]);\
      dstW[0] = srcW[0]; dstW[1] = srcW[1]; dstW[2] = srcW[2]; dstW[3] = srcW[3];\
    }                                                                            \
    __syncthreads();                                                             \
    float4 xjv[8];                                                               \
    _Pragma("unroll")                                                            \
    for (int k = 0; k < 8; ++k)                                                  \
        xjv[k] = nf4[(size_t)t * (CC / 4) + (cc0 >> 2) + k];                     \
    _Pragma("unroll")                                                            \
    for (int c4 = 0; c4 < 8; ++c4) {                                             \
      float a0 = bs2[c0 + c4 * 4 + 0], a1 = bs2[c0 + c4 * 4 + 1];                \
      float a2 = bs2[c0 + c4 * 4 + 2], a3 = bs2[c0 + c4 * 4 + 3];                \
      float r0 = br2[c0 + c4 * 4 + 0], r1 = br2[c0 + c4 * 4 + 1];                \
      float r2 = br2[c0 + c4 * 4 + 2], r3 = br2[c0 + c4 * 4 + 3];                \
      _Pragma("unroll")                                                          \
      for (int jg = 0; jg < 8; ++jg) {                                           \
        float4 wv[4], rv[4];                                                     \
        _Pragma("unroll")                                                        \
        for (int k = 0; k < 4; ++k) {                                            \
          wv[k] = *reinterpret_cast<const float4*>(&sW[0][jg * 4 + k][c4 * 4]);  \
          rv[k] = *reinterpret_cast<const float4*>(&sW[1][jg * 4 + k][c4 * 4]);  \
        }                                                                        \
        _Pragma("unroll")                                                        \
        for (int k = 0; k < 4; ++k) {                                            \
          float hsv = hs[jg * 4 + k], hrv = hr[jg * 4 + k];                      \
          a0 = fmaf(hsv, wv[k].x, a0); a1 = fmaf(hsv, wv[k].y, a1);              \
          a2 = fmaf(hsv, wv[k].z, a2); a3 = fmaf(hsv, wv[k].w, a3);              \
          r0 = fmaf(hrv, rv[k].x, r0); r1 = fmaf(hrv, rv[k].y, r1);              \
          r2 = fmaf(hrv, rv[k].z, r2); r3 = fmaf(hrv, rv[k].w, r3);              \
        }                                                                        \
      }                                                                          \
      sT[w][l][c4 * 4 + 0] = a0 * r0 * xjv[c4].x;                                \
      sT[w][l][c4 * 4 + 1] = a1 * r1 * xjv[c4].y;                                \
      sT[w][l][c4 * 4 + 2] = a2 * r2 * xjv[c4].z;                                \
      sT[w][l][c4 * 4 + 3] = a3 * r3 * xjv[c4].w;                                \
    }                                                                            \
    {                                                                            \
      const int c = l & 31, h = l >> 5, be = h * 32;                             \
      float racc[K];                                                             \
      _Pragma("unroll")                                                          \
      for (int k = 0; k < K; ++k) racc[k] = 0.f;                                 \
      int cur = sSrc[w][be];                                                     \
      _Pragma("unroll 4")                                                        \
      for (int ee = 0; ee < 32; ++ee) {                                          \
        int src = sSrc[w][be + ee];                                              \
        if (src != cur) {                                                        \
          float* ab = g_accu + (size_t)cur * MROW + MOFF + cc0 + c;              \
          _Pragma("unroll")                                                      \
          for (int k = 0; k < K; ++k) {                                          \
            unsafeAtomicAdd(ab + k * CC, racc[k]);                               \
            racc[k] = 0.f;                                                       \
          }                                                                      \
          cur = src;                                                             \
        }                                                                        \
        float u = sT[w][be + ee][c];                                             \
        _Pragma("unroll")                                                        \
        for (int k = 0; k < K; ++k)                                              \
          racc[k] = fmaf(u, yS[w][be + ee][YB + k], racc[k]);                    \
      }                                                                          \
      float* ab = g_accu + (size_t)cur * MROW + MOFF + cc0 + c;                  \
      _Pragma("unroll")                                                          \
      for (int k = 0; k < K; ++k) unsafeAtomicAdd(ab + k * CC, racc[k]);         \
    }                                                                            \
  }

__global__ __launch_bounds__(128) void fused_kernel(
    const float* __restrict__ nf,
    const float* __restrict__ edge_attr,
    const float* __restrict__ edge_rsh,
    const int*   __restrict__ edge_index,
    const float* __restrict__ Ws2, const float* __restrict__ bs2,
    const float* __restrict__ Wr1, const float* __restrict__ br1,
    const float* __restrict__ Wr2, const float* __restrict__ br2)
{
    __shared__ float sW[2][32][36];   // 9.2 KB: 32-col chunks of Ws2,Wr2
    __shared__ float sT[2][64][33];   // 16.9 KB: per-wave 64-edge x 32-col u
    __shared__ float yS[2][64][10];   // 5.1 KB: per-wave SH coeffs
    __shared__ int   sSrc[2][64];     // per-wave src node ids

    int w = threadIdx.x >> 6, l = threadIdx.x & 63;
    int p = blockIdx.x * 128 + threadIdx.x;   // grid exact: EE/128
    int e = g_ord[p];
    int s = edge_index[e];
    int t = edge_index[EE + e];

    // ---- hs = silu(Pi[s] + Pj[t])
    float hs[HIDD];
    {
        const float4* pi = reinterpret_cast<const float4*>(g_proj + (size_t)s * 64);
        const float4* pj = reinterpret_cast<const float4*>(g_proj + (size_t)t * 64 + HIDD);
        #pragma unroll
        for (int j4 = 0; j4 < HIDD / 4; ++j4) {
            float4 a = pi[j4], b = pj[j4];
            hs[4 * j4 + 0] = silu_f(a.x + b.x);
            hs[4 * j4 + 1] = silu_f(a.y + b.y);
            hs[4 * j4 + 2] = silu_f(a.z + b.z);
            hs[4 * j4 + 3] = silu_f(a.w + b.w);
        }
    }

    // ---- hr = silu(edge_attr @ Wr1 + br1)
    float hr[HIDD];
    #pragma unroll
    for (int j = 0; j < HIDD; ++j) hr[j] = br1[j];
    #pragma unroll 1
    for (int k4 = 0; k4 < RBFD / 4; ++k4) {
        float4 a = reinterpret_cast<const float4*>(edge_attr + (size_t)e * RBFD)[k4];
        const float* wp = Wr1 + (4 * k4) * HIDD;
        #pragma unroll
        for (int j = 0; j < HIDD; ++j) {
            hr[j] = fmaf(a.x, wp[j], hr[j]);
            hr[j] = fmaf(a.y, wp[HIDD + j], hr[j]);
            hr[j] = fmaf(a.z, wp[2 * HIDD + j], hr[j]);
            hr[j] = fmaf(a.w, wp[3 * HIDD + j], hr[j]);
        }
    }
    #pragma unroll
    for (int j = 0; j < HIDD; ++j) hr[j] = silu_f(hr[j]);

    // ---- stage per-edge metadata for the in-wave reduction
    sSrc[w][l] = s;
    #pragma unroll
    for (int i = 0; i < 9; ++i) yS[w][l][i] = edge_rsh[(size_t)e * 9 + i];

    const float4* nf4 = reinterpret_cast<const float4*>(nf);
    int jj = (threadIdx.x >> 1) & 31, qq = threadIdx.x & 1;   // staging decomp

    CHUNK_SECTION(0, 1, 0, 0)        // cols   0-127 -> m=0,   y[0]
    CHUNK_SECTION(1, 3, 1, CC)       // cols 128-255 -> m=1-3, y[1..3]
    CHUNK_SECTION(2, 5, 4, 4 * CC)   // cols 256-383 -> m=4-8, y[4..8]
}

// Node-wise linear, 2 nodes per block. (unchanged)
__global__ __launch_bounds__(256) void lin2_kernel(
    const float* __restrict__ W0, const float* __restrict__ b0,
    const float* __restrict__ W1, const float* __restrict__ W2,
    float* __restrict__ out)
{
    __shared__ float sA[2 * MROW];
    int n0 = blockIdx.x * 2;
    const float4* g = reinterpret_cast<const float4*>(g_accu + (size_t)n0 * MROW);
    for (int i = threadIdx.x; i < 2 * MROW / 4; i += 256)
        reinterpret_cast<float4*>(sA)[i] = g[i];
    __syncthreads();

    int d  = threadIdx.x & (CC - 1);
    int nl = threadIdx.x >> 7;
    const float* a = sA + nl * MROW;

    float acc[9];
    #pragma unroll
    for (int m = 0; m < 9; ++m) acc[m] = 0.f;

    #pragma unroll 2
    for (int cc = 0; cc < CC; ++cc) {
        float w0 = W0[cc * CC + d];
        float w1 = W1[cc * CC + d];
        float w2 = W2[cc * CC + d];
        acc[0] = fmaf(a[cc],           w0, acc[0]);
        acc[1] = fmaf(a[CC + cc],      w1, acc[1]);
        acc[2] = fmaf(a[2 * CC + cc],  w1, acc[2]);
        acc[3] = fmaf(a[3 * CC + cc],  w1, acc[3]);
        acc[4] = fmaf(a[4 * CC + cc],  w2, acc[4]);
        acc[5] = fmaf(a[5 * CC + cc],  w2, acc[5]);
        acc[6] = fmaf(a[6 * CC + cc],  w2, acc[6]);
        acc[7] = fmaf(a[7 * CC + cc],  w2, acc[7]);
        acc[8] = fmaf(a[8 * CC + cc],  w2, acc[8]);
    }

    const float inv = 0.08838834764831845f;  // 1/sqrt(128)
    size_t ob = (size_t)(n0 + nl) * MROW;
    out[ob + d] = acc[0] * inv + b0[d];
    #pragma unroll
    for (int m = 0; m < 3; ++m) out[ob + CC + d * 3 + m]     = acc[1 + m] * inv;
    #pragma unroll
    for (int m = 0; m < 5; ++m) out[ob + 4 * CC + d * 5 + m] = acc[4 + m] * inv;
}

extern "C" void kernel_launch(void* const* d_in, const int* in_sizes, int n_in,
                              void* d_out, int out_size, void* d_ws, size_t ws_size,
                              hipStream_t stream)
{
    const float* node_feat  = (const float*)d_in[0];
    const float* edge_attr  = (const float*)d_in[1];
    const float* edge_rsh   = (const float*)d_in[2];
    const int*   edge_index = (const int*)  d_in[3];
    const float* Ws1 = (const float*)d_in[4];
    const float* bs1 = (const float*)d_in[5];
    const float* Ws2 = (const float*)d_in[6];
    const float* bs2 = (const float*)d_in[7];
    const float* Wr1 = (const float*)d_in[8];
    const float* br1 = (const float*)d_in[9];
    const float* Wr2 = (const float*)d_in[10];
    const float* br2 = (const float*)d_in[11];
    const float* W0  = (const float*)d_in[12];
    const float* b0  = (const float*)d_in[13];
    const float* W1  = (const float*)d_in[14];
    const float* W2  = (const float*)d_in[15];
    float* out = (float*)d_out;

    zero_deg_kernel<<<(NN + 255) / 256, 256, 0, stream>>>();
    hist_kernel<<<EE / 256, 256, 0, stream>>>(edge_index);
    scan_kernel<<<1, 256, 0, stream>>>();
    perm_kernel<<<EE / 256, 256, 0, stream>>>(edge_index);
    proj_kernel<<<(NN + 63) / 64, 64, 0, stream>>>(node_feat, Ws1, bs1);
    zero_accu_kernel<<<2048, 256, 0, stream>>>();
    fused_kernel<<<EE / 128, 128, 0, stream>>>(
        node_feat, edge_attr, edge_rsh, edge_index,
        Ws2, bs2, Wr1, br1, Wr2, br2);
    lin2_kernel<<<NN / 2, 256, 0, stream>>>(W0, b0, W1, W2, out);
}